// Round 5
// baseline (252.198 us; speedup 1.0000x reference)
//
#include <hip/hip_runtime.h>

#define NTOT 9216
#define NORMC 0.42044820762685725f   /* 32^-0.25 */
#define RATIO 0.08838834764831845f   /* 128^-0.5 */
#define FEPS 1e-4f

typedef _Float16 h8 __attribute__((ext_vector_type(8)));
typedef _Float16 h4 __attribute__((ext_vector_type(4)));
typedef float f4 __attribute__((ext_vector_type(4)));

// async global->LDS, 16B/lane; lds dest = wave-uniform base + lane*16
__device__ __forceinline__ void gld16(const _Float16* g, _Float16* l) {
  __builtin_amdgcn_global_load_lds((const __attribute__((address_space(1))) void*)g,
                                   (__attribute__((address_space(3))) void*)l, 16, 0, 0);
}

// ---------------------------------------------------------------- small prep (fused)
__global__ __launch_bounds__(256) void prep_small(
    const float* __restrict__ wq, const float* __restrict__ wk,
    const float* __restrict__ wv, const float* __restrict__ proj,
    const float* __restrict__ wo, const float* __restrict__ bo,
    const float* __restrict__ wp, const float* __restrict__ bp,
    _Float16* __restrict__ Wall, _Float16* __restrict__ projh,
    _Float16* __restrict__ Wc, float* __restrict__ bc) {
  int r = blockIdx.x, t = threadIdx.x;
  if (r < 768) {
    const float* src = (r < 256) ? wq + (size_t)r * 256
                     : (r < 512) ? wk + (size_t)(r - 256) * 256
                                 : wv + (size_t)(r - 512) * 256;
    Wall[(size_t)r * 256 + t] = (_Float16)src[t];
  } else if (r < 784) {
    int idx = (r - 768) * 256 + t;
    projh[idx] = (_Float16)proj[idx];
  } else {
    int o = r - 784;
    float acc = 0.f;
    for (int c = 0; c < 256; ++c) acc += wp[o * 256 + c] * wo[c * 256 + t];
    Wc[o * 256 + t] = (_Float16)acc;
    if (t == 0) {
      float ab = bp[o];
      for (int c = 0; c < 256; ++c) ab += wp[o * 256 + c] * bo[c];
      bc[o] = ab;
    }
  }
}

// ---------------------------------------------------------------- x transpose fp32 [b][c][n] -> fp16 [b*n][c]
__global__ __launch_bounds__(256) void prep_xT(
    const float* __restrict__ x, _Float16* __restrict__ xT) {
  __shared__ float T_s[64][65];
  int n0 = blockIdx.x * 64, c0 = blockIdx.y * 64, b = blockIdx.z;
  int t = threadIdx.x;
  for (int i = 0; i < 4; ++i) {
    int f = t + i * 256;
    int cc = f >> 4, n4 = f & 15;
    float4 a = *(const float4*)(x + ((size_t)(b * 256 + c0 + cc)) * NTOT + n0 + n4 * 4);
    T_s[cc][n4 * 4 + 0] = a.x;
    T_s[cc][n4 * 4 + 1] = a.y;
    T_s[cc][n4 * 4 + 2] = a.z;
    T_s[cc][n4 * 4 + 3] = a.w;
  }
  __syncthreads();
  for (int i = 0; i < 2; ++i) {
    int f = t + i * 256;
    int nn = f >> 3, c8 = f & 7;
    h8 hv;
    for (int j = 0; j < 8; ++j) hv[j] = (_Float16)T_s[c8 * 8 + j][nn];
    *(h8*)(xT + ((size_t)(b * NTOT + n0 + nn)) * 256 + c0 + c8 * 8) = hv;
  }
}

// ---------------------------------------------------------------- qkv MFMA gemm
// A = W (co rows), B = xT (n rows) -> D[co][n]; h4 packed stores along co.
__global__ __launch_bounds__(256) void qkv_mfma(
    const _Float16* __restrict__ xT, const _Float16* __restrict__ Wall,
    _Float16* __restrict__ q, _Float16* __restrict__ k, _Float16* __restrict__ v) {
  __shared__ __align__(16) _Float16 A_s[128 * 32];
  __shared__ __align__(16) _Float16 B_s[128 * 32];
  int n0 = blockIdx.x * 128, co0 = blockIdx.y * 128, sel = blockIdx.z;
  _Float16* Out = (sel == 0) ? q : (sel == 1) ? k : v;
  const _Float16* Wb = Wall + (size_t)sel * 65536;
  int t = threadIdx.x, wave = t >> 6, lane = t & 63;
  int lm = lane & 15, lg = lane >> 4;
  int wm = (wave & 1) * 64, wn = (wave >> 1) * 64;
  int srow = wave * 32 + (lane >> 2);
  int scol = ((lane & 3) ^ ((lane >> 3) & 3)) * 8;  // swizzled staging col
  const _Float16* gA = Wb + (size_t)(co0 + srow) * 256 + scol;
  const _Float16* gB = xT + (size_t)(n0 + srow) * 256 + scol;
  _Float16* lA = A_s + wave * 1024;
  _Float16* lB = B_s + wave * 1024;
  int pg = (lg ^ ((lm >> 1) & 3)) * 8;  // swizzled frag group
  f4 acc[4][4] = {};
  for (int kt = 0; kt < 8; ++kt) {
    int c0 = kt * 32;
    __syncthreads();
    gld16(gA + c0, lA);
    gld16(gA + c0 + 16 * 256, lA + 512);
    gld16(gB + c0, lB);
    gld16(gB + c0 + 16 * 256, lB + 512);
    __syncthreads();
    h8 a[4], bf[4];
#pragma unroll
    for (int mi = 0; mi < 4; ++mi) a[mi] = *(const h8*)&A_s[(wm + mi * 16 + lm) * 32 + pg];
#pragma unroll
    for (int ni = 0; ni < 4; ++ni) bf[ni] = *(const h8*)&B_s[(wn + ni * 16 + lm) * 32 + pg];
#pragma unroll
    for (int mi = 0; mi < 4; ++mi)
#pragma unroll
      for (int ni = 0; ni < 4; ++ni)
        acc[mi][ni] = __builtin_amdgcn_mfma_f32_16x16x32_f16(a[mi], bf[ni], acc[mi][ni], 0, 0, 0);
  }
#pragma unroll
  for (int mi = 0; mi < 4; ++mi)
#pragma unroll
    for (int ni = 0; ni < 4; ++ni) {
      h4 hv;
#pragma unroll
      for (int r = 0; r < 4; ++r) hv[r] = (_Float16)acc[mi][ni][r];
      *(h4*)(Out + (size_t)(n0 + wn + ni * 16 + lm) * 256 + co0 + wm + mi * 16 + lg * 4) = hv;
    }
}

// ---------------------------------------------------------------- v transpose: [b*n][c] -> [b*256+c][n]
__global__ __launch_bounds__(256) void prep_vT(
    const _Float16* __restrict__ v, _Float16* __restrict__ vT) {
  __shared__ _Float16 T[64 * 132];
  int n0 = blockIdx.x * 128, c0 = blockIdx.y * 64, b = blockIdx.z;
  int t = threadIdx.x;
  for (int i = 0; i < 4; ++i) {
    int f = t + i * 256;
    int nl = f >> 3, cg = f & 7;
    h8 vv = *(const h8*)(v + ((size_t)(b * NTOT + n0 + nl)) * 256 + c0 + cg * 8);
#pragma unroll
    for (int j = 0; j < 8; ++j) T[(cg * 8 + j) * 132 + nl] = vv[j];
  }
  __syncthreads();
  int cl = t >> 2, seg = t & 3;
  _Float16* gout = vT + ((size_t)(b * 256 + c0 + cl)) * NTOT + n0 + seg * 32;
#pragma unroll
  for (int j = 0; j < 8; ++j)
    *(h4*)(gout + j * 4) = *(const h4*)&T[cl * 132 + seg * 32 + j * 4];
}

// ---------------------------------------------------------------- kmax via MFMA
__global__ __launch_bounds__(256) void kmax_mfma(
    const _Float16* __restrict__ k, const _Float16* __restrict__ projh,
    float* __restrict__ kmaxp) {
  __shared__ __align__(16) _Float16 k_s[128 * 32];
  __shared__ float red4[4];
  int bh = blockIdx.y, b = bh >> 3, h = bh & 7;
  int nbase = blockIdx.x * 256;
  int t = threadIdx.x, wave = t >> 6, lane = t & 63, lm = lane & 15, lg = lane >> 4;
  h8 pr[8];
#pragma unroll
  for (int mt = 0; mt < 8; ++mt) pr[mt] = *(const h8*)&projh[(mt * 16 + lm) * 32 + lg * 8];
  int scol = ((lane & 3) ^ ((lane >> 3) & 3)) * 8;
  const _Float16* gK =
      k + ((size_t)(b * NTOT + nbase + wave * 32 + (lane >> 2))) * 256 + h * 32 + scol;
  _Float16* lK = k_s + wave * 1024;
  int pg = (lg ^ ((lm >> 1) & 3)) * 8;
  float vmax = -1e30f;
  for (int ch = 0; ch < 2; ++ch) {
    __syncthreads();
    gld16(gK + (size_t)(ch * 128) * 256, lK);
    gld16(gK + (size_t)(ch * 128) * 256 + 16 * 256, lK + 512);
    __syncthreads();
#pragma unroll
    for (int nt = 0; nt < 2; ++nt) {
      h8 a = *(const h8*)&k_s[(wave * 32 + nt * 16 + lm) * 32 + pg];
#pragma unroll
      for (int mt = 0; mt < 8; ++mt) {
        f4 z = {0.f, 0.f, 0.f, 0.f};
        f4 d = __builtin_amdgcn_mfma_f32_16x16x32_f16(a, pr[mt], z, 0, 0, 0);
        vmax = fmaxf(vmax, fmaxf(fmaxf(d[0], d[1]), fmaxf(d[2], d[3])));
      }
    }
  }
  for (int i = 1; i < 64; i <<= 1) vmax = fmaxf(vmax, __shfl_xor(vmax, i, 64));
  if (lane == 0) red4[wave] = vmax;
  __syncthreads();
  if (t == 0)
    kmaxp[bh * 36 + blockIdx.x] =
        NORMC * fmaxf(fmaxf(red4[0], red4[1]), fmaxf(red4[2], red4[3]));
}

// ---------------------------------------------------------------- ctx: partials, no atomics
// part[block][d(0..31)][m] = sum_n kp[n][m] v[n][d]; part[block][32][m] = sum_n kp
__global__ __launch_bounds__(256) void ctx_mfma(
    const _Float16* __restrict__ k, const _Float16* __restrict__ vT,
    const _Float16* __restrict__ projh, const float* __restrict__ kmaxp,
    float* __restrict__ part) {
  __shared__ __align__(16) _Float16 k_s[128 * 32];    // 8KB
  __shared__ __align__(16) _Float16 vT_s[32 * 136];   // 8.5KB
  __shared__ __align__(16) _Float16 kpT[128 * 136];   // 34KB (reused as ksum red at end)
  __shared__ float diag_s[128];
  __shared__ float kmax_sh;
  int bh = blockIdx.y, b = bh >> 3, h = bh & 7;
  int nbase = blockIdx.x * 384;
  int t = threadIdx.x, wave = t >> 6, lane = t & 63, lm = lane & 15, lg = lane >> 4;
  h8 pr[8];
#pragma unroll
  for (int mt = 0; mt < 8; ++mt) pr[mt] = *(const h8*)&projh[(mt * 16 + lm) * 32 + lg * 8];
  if (t == 0) {
    float mx = -1e30f;
    for (int i = 0; i < 36; ++i) mx = fmaxf(mx, kmaxp[bh * 36 + i]);
    kmax_sh = mx;
  }
  __syncthreads();
  float kmax = kmax_sh;
  int scol = ((lane & 3) ^ ((lane >> 3) & 3)) * 8;
  const _Float16* gK =
      k + ((size_t)(b * NTOT + nbase + wave * 32 + (lane >> 2))) * 256 + h * 32 + scol;
  const _Float16* gV = vT + ((size_t)(b * 256 + h * 32 + (t >> 3))) * NTOT + nbase;
  _Float16* lK = k_s + wave * 1024;
  int pg = (lg ^ ((lm >> 1) & 3)) * 8;
  f4 cacc[2][2] = {};
  float ks[8] = {};
  for (int ch = 0; ch < 3; ++ch) {
    gld16(gK + (size_t)(ch * 128) * 256, lK);
    gld16(gK + (size_t)(ch * 128) * 256 + 16 * 256, lK + 512);
    {
      int d = t >> 3, g = t & 7;
#pragma unroll
      for (int i = 0; i < 2; ++i) {
        h8 vv = *(const h8*)(gV + ch * 128 + (i * 8 + g) * 8);
        *(h8*)&vT_s[d * 136 + (i * 8 + g) * 8] = vv;
      }
    }
    __syncthreads();
    if (t < 128) {
      float s = 0.f;
#pragma unroll
      for (int c = 0; c < 4; ++c) {
        h8 kv = *(const h8*)&k_s[t * 32 + c * 8];
#pragma unroll
        for (int j = 0; j < 8; ++j) s += (float)kv[j] * (float)kv[j];
      }
      diag_s[t] = s * (0.5f * NORMC * NORMC);
    }
    f4 dsh[2][8];
#pragma unroll
    for (int nt = 0; nt < 2; ++nt) {
      h8 a = *(const h8*)&k_s[(wave * 32 + nt * 16 + lm) * 32 + pg];
#pragma unroll
      for (int mt = 0; mt < 8; ++mt) {
        f4 z = {0.f, 0.f, 0.f, 0.f};
        dsh[nt][mt] = __builtin_amdgcn_mfma_f32_16x16x32_f16(a, pr[mt], z, 0, 0, 0);
      }
    }
    __syncthreads();
#pragma unroll
    for (int nt = 0; nt < 2; ++nt)
#pragma unroll
      for (int mt = 0; mt < 8; ++mt) {
        h4 hv;
        float lsum = 0.f;
#pragma unroll
        for (int r = 0; r < 4; ++r) {
          int nl = wave * 32 + nt * 16 + lg * 4 + r;
          float val = RATIO * (__expf(NORMC * dsh[nt][mt][r] - diag_s[nl] - kmax) + FEPS);
          hv[r] = (_Float16)val;
          lsum += val;
        }
        ks[mt] += lsum;
        *(h4*)&kpT[(mt * 16 + lm) * 136 + wave * 32 + nt * 16 + lg * 4] = hv;
      }
    __syncthreads();
#pragma unroll
    for (int k2 = 0; k2 < 4; ++k2) {
      h8 a2[2], b2[2];
#pragma unroll
      for (int mt2 = 0; mt2 < 2; ++mt2)
        a2[mt2] = *(const h8*)&kpT[(wave * 32 + mt2 * 16 + lm) * 136 + k2 * 32 + lg * 8];
#pragma unroll
      for (int dt = 0; dt < 2; ++dt)
        b2[dt] = *(const h8*)&vT_s[(dt * 16 + lm) * 136 + k2 * 32 + lg * 8];
#pragma unroll
      for (int mt2 = 0; mt2 < 2; ++mt2)
#pragma unroll
        for (int dt = 0; dt < 2; ++dt)
          cacc[mt2][dt] =
              __builtin_amdgcn_mfma_f32_16x16x32_f16(a2[mt2], b2[dt], cacc[mt2][dt], 0, 0, 0);
    }
    __syncthreads();
  }
  // store partials (plain f4 stores)
  float* pp = part + (size_t)(blockIdx.y * 24 + blockIdx.x) * 4224;
#pragma unroll
  for (int mt2 = 0; mt2 < 2; ++mt2)
#pragma unroll
    for (int dt = 0; dt < 2; ++dt)
      *(f4*)(pp + (dt * 16 + lm) * 128 + wave * 32 + mt2 * 16 + lg * 4) = cacc[mt2][dt];
  // ksum: xor-reduce over lg, cross-wave via kpT-as-float overlay
  float* redk = (float*)kpT;
#pragma unroll
  for (int mt = 0; mt < 8; ++mt) {
    float s = ks[mt];
    s += __shfl_xor(s, 16, 64);
    s += __shfl_xor(s, 32, 64);
    if (lg == 0) redk[wave * 128 + mt * 16 + lm] = s;
  }
  __syncthreads();
  if (t < 128)
    pp[32 * 128 + t] = redk[t] + redk[128 + t] + redk[256 + t] + redk[384 + t];
}

// ---------------------------------------------------------------- reduce partials -> ctx_aug[m][36]
__global__ __launch_bounds__(256) void reduce_ctx(
    const float* __restrict__ part, float* __restrict__ ctx_aug) {
  int bh = blockIdx.x, t = threadIdx.x;
  const float* pb = part + (size_t)bh * 24 * 4224;
  for (int it = 0; it < 17; ++it) {
    int cell = t + it * 256;
    if (cell < 4224) {
      float s = 0.f;
      for (int p = 0; p < 24; ++p) s += pb[(size_t)p * 4224 + cell];
      int d = cell >> 7, m = cell & 127;
      ctx_aug[(size_t)bh * 4608 + m * 36 + d] = s;
    }
  }
}

// ---------------------------------------------------------------- q side
// dash swapped: D[m][n] -> packed h4 qp[n][m]; out swapped: D[d][n] -> h4 stores
__global__ __launch_bounds__(256) void attn_mfma(
    const _Float16* __restrict__ q, const _Float16* __restrict__ projh,
    const float* __restrict__ ctx_aug, _Float16* __restrict__ attn) {
  __shared__ __align__(16) _Float16 q_sh[128 * 32];   // 8KB
  __shared__ __align__(16) _Float16 qp_s[128 * 136];  // 34KB
  __shared__ __align__(16) _Float16 ctxT[32 * 136];   // 8.5KB
  __shared__ float ksum_s[128];
  int n0 = blockIdx.x * 128;
  int bh = blockIdx.y, b = bh >> 3, h = bh & 7;
  int t = threadIdx.x, wave = t >> 6, lane = t & 63, lm = lane & 15, lg = lane >> 4;
  const float* cb = ctx_aug + (size_t)bh * 4608;
  h8 pr[8];
#pragma unroll
  for (int mt = 0; mt < 8; ++mt) pr[mt] = *(const h8*)&projh[(mt * 16 + lm) * 32 + lg * 8];
  int scol = ((lane & 3) ^ ((lane >> 3) & 3)) * 8;
  const _Float16* gQ =
      q + ((size_t)(b * NTOT + n0 + wave * 32 + (lane >> 2))) * 256 + h * 32 + scol;
  gld16(gQ, q_sh + wave * 1024);
  gld16(gQ + 16 * 256, q_sh + wave * 1024 + 512);
  {
    int m = t >> 1, dbase = (t & 1) * 16;
#pragma unroll
    for (int g = 0; g < 4; ++g) {
      float4 cv = *(const float4*)(cb + m * 36 + dbase + g * 4);
      ctxT[(dbase + g * 4 + 0) * 136 + m] = (_Float16)cv.x;
      ctxT[(dbase + g * 4 + 1) * 136 + m] = (_Float16)cv.y;
      ctxT[(dbase + g * 4 + 2) * 136 + m] = (_Float16)cv.z;
      ctxT[(dbase + g * 4 + 3) * 136 + m] = (_Float16)cv.w;
    }
  }
  if (t < 128) ksum_s[t] = cb[t * 36 + 32];
  __syncthreads();
  int pg = (lg ^ ((lm >> 1) & 3)) * 8;
  // in-register diag for this lane's n (per nt)
  float diag_r[2];
#pragma unroll
  for (int nt = 0; nt < 2; ++nt) {
    int n = wave * 32 + nt * 16 + lm;
    float s = 0.f;
#pragma unroll
    for (int c = 0; c < 4; ++c) {
      h8 qv = *(const h8*)&q_sh[n * 32 + c * 8];
#pragma unroll
      for (int j = 0; j < 8; ++j) s += (float)qv[j] * (float)qv[j];
    }
    diag_r[nt] = s * (0.5f * NORMC * NORMC);
  }
  f4 dsh[2][8];
#pragma unroll
  for (int nt = 0; nt < 2; ++nt) {
    h8 qf = *(const h8*)&q_sh[(wave * 32 + nt * 16 + lm) * 32 + pg];
#pragma unroll
    for (int mt = 0; mt < 8; ++mt) {
      f4 z = {0.f, 0.f, 0.f, 0.f};
      dsh[nt][mt] = __builtin_amdgcn_mfma_f32_16x16x32_f16(pr[mt], qf, z, 0, 0, 0);
    }
  }
  float den_r[2];
#pragma unroll
  for (int nt = 0; nt < 2; ++nt) {
    float mx = -1e30f;
#pragma unroll
    for (int mt = 0; mt < 8; ++mt)
#pragma unroll
      for (int r = 0; r < 4; ++r) mx = fmaxf(mx, dsh[nt][mt][r]);
    mx = fmaxf(mx, __shfl_xor(mx, 16, 64));
    mx = fmaxf(mx, __shfl_xor(mx, 32, 64));
    float den = 0.f;
#pragma unroll
    for (int mt = 0; mt < 8; ++mt) {
      h4 hv;
#pragma unroll
      for (int r = 0; r < 4; ++r) {
        float val = RATIO * (__expf(NORMC * (dsh[nt][mt][r] - mx) - diag_r[nt]) + FEPS);
        hv[r] = (_Float16)val;
        den += val * ksum_s[mt * 16 + lg * 4 + r];
      }
      *(h4*)&qp_s[(wave * 32 + nt * 16 + lm) * 136 + mt * 16 + lg * 4] = hv;
    }
    den += __shfl_xor(den, 16, 64);
    den += __shfl_xor(den, 32, 64);
    den_r[nt] = 1.f / den;
  }
  __syncthreads();
  f4 oacc[2][2] = {};
#pragma unroll
  for (int k2 = 0; k2 < 4; ++k2) {
    h8 ac[2], bq[2];
#pragma unroll
    for (int dt = 0; dt < 2; ++dt)
      ac[dt] = *(const h8*)&ctxT[(dt * 16 + lm) * 136 + k2 * 32 + lg * 8];
#pragma unroll
    for (int nt = 0; nt < 2; ++nt)
      bq[nt] = *(const h8*)&qp_s[(wave * 32 + nt * 16 + lm) * 136 + k2 * 32 + lg * 8];
#pragma unroll
    for (int dt = 0; dt < 2; ++dt)
#pragma unroll
      for (int nt = 0; nt < 2; ++nt)
        oacc[dt][nt] = __builtin_amdgcn_mfma_f32_16x16x32_f16(ac[dt], bq[nt], oacc[dt][nt], 0, 0, 0);
  }
#pragma unroll
  for (int dt = 0; dt < 2; ++dt)
#pragma unroll
    for (int nt = 0; nt < 2; ++nt) {
      int n = wave * 32 + nt * 16 + lm;
      h4 hv;
#pragma unroll
      for (int r = 0; r < 4; ++r) hv[r] = (_Float16)(oacc[dt][nt][r] * den_r[nt]);
      *(h4*)(attn + ((size_t)(b * NTOT + n0 + n)) * 256 + h * 32 + dt * 16 + lg * 4) = hv;
    }
}

// ---------------------------------------------------------------- output gemm
// A = attn (n rows), B = Wc (o rows) -> D[n][o]: float4 stores along n
__global__ __launch_bounds__(256) void out_mfma(
    const _Float16* __restrict__ Wc, const _Float16* __restrict__ attn,
    const float* __restrict__ bc, float* __restrict__ out) {
  __shared__ __align__(16) _Float16 A_s[128 * 32];  // Wc
  __shared__ __align__(16) _Float16 B_s[128 * 32];  // attn
  int bx = blockIdx.x;
  int o0 = blockIdx.y * 128;
  int b = bx / 72, nb0 = (bx % 72) * 128;
  int t = threadIdx.x, wave = t >> 6, lane = t & 63;
  int lm = lane & 15, lg = lane >> 4;
  int wm = (wave & 1) * 64, wn = (wave >> 1) * 64;
  int srow = wave * 32 + (lane >> 2);
  int scol = ((lane & 3) ^ ((lane >> 3) & 3)) * 8;
  const _Float16* gA = Wc + (size_t)(o0 + srow) * 256 + scol;
  const _Float16* gB = attn + (size_t)(b * NTOT + nb0 + srow) * 256 + scol;
  _Float16* lA = A_s + wave * 1024;
  _Float16* lB = B_s + wave * 1024;
  int pg = (lg ^ ((lm >> 1) & 3)) * 8;
  f4 acc[4][4] = {};
  for (int kt = 0; kt < 8; ++kt) {
    int c0 = kt * 32;
    __syncthreads();
    gld16(gA + c0, lA);
    gld16(gA + c0 + 16 * 256, lA + 512);
    gld16(gB + c0, lB);
    gld16(gB + c0 + 16 * 256, lB + 512);
    __syncthreads();
    h8 a[4], bf[4];
#pragma unroll
    for (int mi = 0; mi < 4; ++mi) a[mi] = *(const h8*)&A_s[(wm + mi * 16 + lm) * 32 + pg];
#pragma unroll
    for (int ni = 0; ni < 4; ++ni) bf[ni] = *(const h8*)&B_s[(wn + ni * 16 + lm) * 32 + pg];
#pragma unroll
    for (int mi = 0; mi < 4; ++mi)
#pragma unroll
      for (int ni = 0; ni < 4; ++ni)
        acc[mi][ni] = __builtin_amdgcn_mfma_f32_16x16x32_f16(bf[ni], a[mi], acc[mi][ni], 0, 0, 0);
  }
#pragma unroll
  for (int mi = 0; mi < 4; ++mi) {
    int o = o0 + wm + mi * 16 + lm;
    float bias = bc[o];
#pragma unroll
    for (int ni = 0; ni < 4; ++ni) {
      f4 ov = acc[mi][ni];
      float4 st = make_float4(ov[0] + bias, ov[1] + bias, ov[2] + bias, ov[3] + bias);
      *(float4*)(out + ((size_t)(b * 256 + o)) * NTOT + nb0 + wn + ni * 16 + lg * 4) = st;
    }
  }
}

// ---------------------------------------------------------------- launch
extern "C" void kernel_launch(void* const* d_in, const int* in_sizes, int n_in,
                              void* d_out, int out_size, void* d_ws, size_t ws_size,
                              hipStream_t stream) {
  const float* x = (const float*)d_in[0];
  const float* wq = (const float*)d_in[1];
  const float* wk = (const float*)d_in[2];
  const float* wv = (const float*)d_in[3];
  const float* wo = (const float*)d_in[4];
  const float* bo = (const float*)d_in[5];
  const float* proj = (const float*)d_in[6];
  const float* wp = (const float*)d_in[7];
  const float* bp = (const float*)d_in[8];
  float* out = (float*)d_out;
  float* ws = (float*)d_ws;

  float* part = ws;                        // 768*4224 = 3,244,032
  float* ctx_aug = part + 3244032;         // 32*4608 = 147,456
  float* kmaxp = ctx_aug + 147456;         // 32*36
  float* bc = kmaxp + 1152;                // 256
  _Float16* hb = (_Float16*)(bc + 256);
  const size_t THALF = (size_t)4 * NTOT * 256;  // 9,437,184
  _Float16* q_h = hb;
  _Float16* k_h = q_h + THALF;
  _Float16* v_h = k_h + THALF;
  _Float16* xT = v_h + THALF;          // reused as attn fp16 output
  _Float16* vTg = xT + THALF;          // v transposed [b*256+c][n]
  _Float16* Wall = vTg + THALF;        // 768*256
  _Float16* Wc = Wall + 768 * 256;     // 256*256
  _Float16* projh = Wc + 65536;        // 128*32

  prep_small<<<1040, 256, 0, stream>>>(wq, wk, wv, proj, wo, bo, wp, bp, Wall, projh, Wc, bc);
  prep_xT<<<dim3(144, 4, 4), 256, 0, stream>>>(x, xT);
  qkv_mfma<<<dim3(288, 2, 3), 256, 0, stream>>>(xT, Wall, q_h, k_h, v_h);
  prep_vT<<<dim3(72, 4, 4), 256, 0, stream>>>(v_h, vTg);
  kmax_mfma<<<dim3(36, 32), 256, 0, stream>>>(k_h, projh, kmaxp);
  ctx_mfma<<<dim3(24, 32), 256, 0, stream>>>(k_h, vTg, projh, kmaxp, part);
  reduce_ctx<<<32, 256, 0, stream>>>(part, ctx_aug);
  attn_mfma<<<dim3(72, 32), 256, 0, stream>>>(q_h, projh, ctx_aug, xT);
  out_mfma<<<dim3(288, 2), 256, 0, stream>>>(Wc, xT, bc, out);
}

// Round 6
// 222.396 us; speedup vs baseline: 1.1340x; 1.1340x over previous
//
#include <hip/hip_runtime.h>

#define NTOT 9216
#define NORMC 0.42044820762685725f   /* 32^-0.25 */
#define RATIO 0.08838834764831845f   /* 128^-0.5 */
#define FEPS 1e-4f

typedef _Float16 h8 __attribute__((ext_vector_type(8)));
typedef _Float16 h4 __attribute__((ext_vector_type(4)));
typedef float f4 __attribute__((ext_vector_type(4)));

// async global->LDS, 16B/lane; lds dest = wave-uniform base + lane*16
__device__ __forceinline__ void gld16(const _Float16* g, _Float16* l) {
  __builtin_amdgcn_global_load_lds((const __attribute__((address_space(1))) void*)g,
                                   (__attribute__((address_space(3))) void*)l, 16, 0, 0);
}

// ---------------------------------------------------------------- fused prep
// r < 2304: x transpose tiles; then Wall rows; projh; Wc rows.
__global__ __launch_bounds__(256) void prep(
    const float* __restrict__ x, const float* __restrict__ wq,
    const float* __restrict__ wk, const float* __restrict__ wv,
    const float* __restrict__ proj, const float* __restrict__ wo,
    const float* __restrict__ bo, const float* __restrict__ wp,
    const float* __restrict__ bp, _Float16* __restrict__ xT,
    _Float16* __restrict__ Wall, _Float16* __restrict__ projh,
    _Float16* __restrict__ Wc, float* __restrict__ bc) {
  __shared__ float T_s[64][65];
  int r = blockIdx.x, t = threadIdx.x;
  if (r < 2304) {
    int nx = r % 144, rem = r / 144;
    int cy = rem & 3, b = rem >> 2;
    int n0 = nx * 64, c0 = cy * 64;
    for (int i = 0; i < 4; ++i) {
      int f = t + i * 256;
      int cc = f >> 4, n4 = f & 15;
      float4 a = *(const float4*)(x + ((size_t)(b * 256 + c0 + cc)) * NTOT + n0 + n4 * 4);
      T_s[cc][n4 * 4 + 0] = a.x;
      T_s[cc][n4 * 4 + 1] = a.y;
      T_s[cc][n4 * 4 + 2] = a.z;
      T_s[cc][n4 * 4 + 3] = a.w;
    }
    __syncthreads();
    for (int i = 0; i < 2; ++i) {
      int f = t + i * 256;
      int nn = f >> 3, c8 = f & 7;
      h8 hv;
      for (int j = 0; j < 8; ++j) hv[j] = (_Float16)T_s[c8 * 8 + j][nn];
      *(h8*)(xT + ((size_t)(b * NTOT + n0 + nn)) * 256 + c0 + c8 * 8) = hv;
    }
    return;
  }
  int r2 = r - 2304;
  if (r2 < 768) {
    const float* src = (r2 < 256) ? wq + (size_t)r2 * 256
                     : (r2 < 512) ? wk + (size_t)(r2 - 256) * 256
                                  : wv + (size_t)(r2 - 512) * 256;
    Wall[(size_t)r2 * 256 + t] = (_Float16)src[t];
  } else if (r2 < 784) {
    int idx = (r2 - 768) * 256 + t;
    projh[idx] = (_Float16)proj[idx];
  } else {
    int o = r2 - 784;
    float acc = 0.f;
    for (int c = 0; c < 256; ++c) acc += wp[o * 256 + c] * wo[c * 256 + t];
    Wc[o * 256 + t] = (_Float16)acc;
    if (t == 0) {
      float ab = bp[o];
      for (int c = 0; c < 256; ++c) ab += wp[o * 256 + c] * bo[c];
      bc[o] = ab;
    }
  }
}

// ---------------------------------------------------------------- qkv MFMA gemm
// sel 0/1: D[co][n], h4 stores along co into q/k [n][256].
// sel 1 extra: spill k tile to LDS, dash GEMM per wave (1 head), kmax partial.
// sel 2: operand-swapped D[n][co], h4 stores along n into vT [c][n].
__global__ __launch_bounds__(256) void qkv_mfma(
    const _Float16* __restrict__ xT, const _Float16* __restrict__ Wall,
    const _Float16* __restrict__ projh, _Float16* __restrict__ q,
    _Float16* __restrict__ k, _Float16* __restrict__ vT,
    float* __restrict__ kmaxp) {
  __shared__ __align__(16) _Float16 A_s[128 * 32];
  __shared__ __align__(16) _Float16 B_s[128 * 32];
  __shared__ __align__(16) _Float16 ktile[64 * 132];
  int bx = blockIdx.x, co0 = blockIdx.y * 128, sel = blockIdx.z;
  int b = bx / 72, ntile = bx % 72;
  int n0 = bx * 128;
  const _Float16* Wb = Wall + (size_t)sel * 65536;
  int t = threadIdx.x, wave = t >> 6, lane = t & 63;
  int lm = lane & 15, lg = lane >> 4;
  int wm = (wave & 1) * 64, wn = (wave >> 1) * 64;
  int srow = wave * 32 + (lane >> 2);
  int scol = ((lane & 3) ^ ((lane >> 3) & 3)) * 8;
  const _Float16* gA = Wb + (size_t)(co0 + srow) * 256 + scol;
  const _Float16* gB = xT + (size_t)(n0 + srow) * 256 + scol;
  _Float16* lA = A_s + wave * 1024;
  _Float16* lB = B_s + wave * 1024;
  int pg = (lg ^ ((lm >> 1) & 3)) * 8;
  f4 acc[4][4] = {};
  if (sel < 2) {
    for (int kt = 0; kt < 8; ++kt) {
      int c0 = kt * 32;
      __syncthreads();
      gld16(gA + c0, lA);
      gld16(gA + c0 + 16 * 256, lA + 512);
      gld16(gB + c0, lB);
      gld16(gB + c0 + 16 * 256, lB + 512);
      __syncthreads();
      h8 a[4], bf[4];
#pragma unroll
      for (int mi = 0; mi < 4; ++mi) a[mi] = *(const h8*)&A_s[(wm + mi * 16 + lm) * 32 + pg];
#pragma unroll
      for (int ni = 0; ni < 4; ++ni) bf[ni] = *(const h8*)&B_s[(wn + ni * 16 + lm) * 32 + pg];
#pragma unroll
      for (int mi = 0; mi < 4; ++mi)
#pragma unroll
        for (int ni = 0; ni < 4; ++ni)
          acc[mi][ni] = __builtin_amdgcn_mfma_f32_16x16x32_f16(a[mi], bf[ni], acc[mi][ni], 0, 0, 0);
    }
    _Float16* Out = (sel == 0) ? q : k;
#pragma unroll
    for (int mi = 0; mi < 4; ++mi)
#pragma unroll
      for (int ni = 0; ni < 4; ++ni) {
        h4 hv;
#pragma unroll
        for (int r = 0; r < 4; ++r) hv[r] = (_Float16)acc[mi][ni][r];
        *(h4*)(Out + (size_t)(n0 + wn + ni * 16 + lm) * 256 + co0 + wm + mi * 16 + lg * 4) = hv;
      }
    if (sel == 1) {
      h8 pr[8];
#pragma unroll
      for (int mt = 0; mt < 8; ++mt)
        pr[mt] = *(const h8*)&projh[(mt * 16 + lm) * 32 + lg * 8];
      float vmax = -1e30f;
      for (int half = 0; half < 2; ++half) {
        __syncthreads();
        if ((wave >> 1) == half) {
#pragma unroll
          for (int mi = 0; mi < 4; ++mi)
#pragma unroll
            for (int ni = 0; ni < 4; ++ni) {
              h4 hv;
#pragma unroll
              for (int r = 0; r < 4; ++r) hv[r] = (_Float16)acc[mi][ni][r];
              *(h4*)&ktile[(ni * 16 + lm) * 132 + wm + mi * 16 + lg * 4] = hv;
            }
        }
        __syncthreads();
#pragma unroll
        for (int nt2 = 0; nt2 < 4; ++nt2) {
          h8 a = *(const h8*)&ktile[(nt2 * 16 + lm) * 132 + wave * 32 + lg * 8];
#pragma unroll
          for (int mt = 0; mt < 8; ++mt) {
            f4 z = {0.f, 0.f, 0.f, 0.f};
            f4 d = __builtin_amdgcn_mfma_f32_16x16x32_f16(a, pr[mt], z, 0, 0, 0);
            vmax = fmaxf(vmax, fmaxf(fmaxf(d[0], d[1]), fmaxf(d[2], d[3])));
          }
        }
      }
      for (int i = 1; i < 64; i <<= 1) vmax = fmaxf(vmax, __shfl_xor(vmax, i, 64));
      if (lane == 0) {
        int h = (co0 >> 5) + wave;
        kmaxp[(size_t)(b * 8 + h) * 72 + ntile] = NORMC * vmax;
      }
    }
  } else {
    for (int kt = 0; kt < 8; ++kt) {
      int c0 = kt * 32;
      __syncthreads();
      gld16(gA + c0, lA);
      gld16(gA + c0 + 16 * 256, lA + 512);
      gld16(gB + c0, lB);
      gld16(gB + c0 + 16 * 256, lB + 512);
      __syncthreads();
      h8 a[4], bf[4];
#pragma unroll
      for (int mi = 0; mi < 4; ++mi) a[mi] = *(const h8*)&A_s[(wm + mi * 16 + lm) * 32 + pg];
#pragma unroll
      for (int ni = 0; ni < 4; ++ni) bf[ni] = *(const h8*)&B_s[(wn + ni * 16 + lm) * 32 + pg];
#pragma unroll
      for (int mi = 0; mi < 4; ++mi)
#pragma unroll
        for (int ni = 0; ni < 4; ++ni)
          acc[mi][ni] = __builtin_amdgcn_mfma_f32_16x16x32_f16(bf[ni], a[mi], acc[mi][ni], 0, 0, 0);
    }
#pragma unroll
    for (int mi = 0; mi < 4; ++mi)
#pragma unroll
      for (int ni = 0; ni < 4; ++ni) {
        h4 hv;
#pragma unroll
        for (int r = 0; r < 4; ++r) hv[r] = (_Float16)acc[mi][ni][r];
        *(h4*)(vT + ((size_t)(b * 256 + co0 + wm + mi * 16 + lm)) * NTOT +
               ntile * 128 + wn + ni * 16 + lg * 4) = hv;
      }
  }
}

// ---------------------------------------------------------------- ctx: partials
// part[blk][d(0..31)][m] = sum_n kp[n][m] v[n][d]; part[blk][32][m] = sum_n kp
__global__ __launch_bounds__(256) void ctx_mfma(
    const _Float16* __restrict__ k, const _Float16* __restrict__ vT,
    const _Float16* __restrict__ projh, const float* __restrict__ kmaxp,
    float* __restrict__ part) {
  __shared__ __align__(16) _Float16 k_s[128 * 32];
  __shared__ __align__(16) _Float16 vT_s[32 * 136];
  __shared__ __align__(16) _Float16 kpT[128 * 136];
  __shared__ float diag_s[128];
  __shared__ float kmax_sh;
  int bh = blockIdx.y, b = bh >> 3, h = bh & 7;
  int nbase = blockIdx.x * 384;
  int t = threadIdx.x, wave = t >> 6, lane = t & 63, lm = lane & 15, lg = lane >> 4;
  h8 pr[8];
#pragma unroll
  for (int mt = 0; mt < 8; ++mt) pr[mt] = *(const h8*)&projh[(mt * 16 + lm) * 32 + lg * 8];
  {
    float* kred = (float*)kpT;
    if (t < 72) kred[t] = kmaxp[(size_t)bh * 72 + t];
    __syncthreads();
    if (t == 0) {
      float mx = -1e30f;
      for (int i = 0; i < 72; ++i) mx = fmaxf(mx, kred[i]);
      kmax_sh = mx;
    }
    __syncthreads();
  }
  float kmax = kmax_sh;
  int scol = ((lane & 3) ^ ((lane >> 3) & 3)) * 8;
  const _Float16* gK =
      k + ((size_t)(b * NTOT + nbase + wave * 32 + (lane >> 2))) * 256 + h * 32 + scol;
  const _Float16* gV = vT + ((size_t)(b * 256 + h * 32 + (t >> 3))) * NTOT + nbase;
  _Float16* lK = k_s + wave * 1024;
  int pg = (lg ^ ((lm >> 1) & 3)) * 8;
  f4 cacc[2][2] = {};
  float ks[8] = {};
  for (int ch = 0; ch < 3; ++ch) {
    gld16(gK + (size_t)(ch * 128) * 256, lK);
    gld16(gK + (size_t)(ch * 128) * 256 + 16 * 256, lK + 512);
    {
      int d = t >> 3, g = t & 7;
#pragma unroll
      for (int i = 0; i < 2; ++i)
        *(h8*)&vT_s[d * 136 + (i * 8 + g) * 8] = *(const h8*)(gV + ch * 128 + (i * 8 + g) * 8);
    }
    __syncthreads();
    if (t < 128) {
      float s = 0.f;
#pragma unroll
      for (int c = 0; c < 4; ++c) {
        h8 kv = *(const h8*)&k_s[t * 32 + c * 8];
#pragma unroll
        for (int j = 0; j < 8; ++j) s += (float)kv[j] * (float)kv[j];
      }
      diag_s[t] = s * (0.5f * NORMC * NORMC);
    }
    f4 dsh[2][8];
#pragma unroll
    for (int nt = 0; nt < 2; ++nt) {
      h8 a = *(const h8*)&k_s[(wave * 32 + nt * 16 + lm) * 32 + pg];
#pragma unroll
      for (int mt = 0; mt < 8; ++mt) {
        f4 z = {0.f, 0.f, 0.f, 0.f};
        dsh[nt][mt] = __builtin_amdgcn_mfma_f32_16x16x32_f16(a, pr[mt], z, 0, 0, 0);
      }
    }
    __syncthreads();
#pragma unroll
    for (int nt = 0; nt < 2; ++nt)
#pragma unroll
      for (int mt = 0; mt < 8; ++mt) {
        h4 hv;
        float lsum = 0.f;
#pragma unroll
        for (int r = 0; r < 4; ++r) {
          int nl = wave * 32 + nt * 16 + lg * 4 + r;
          float val = RATIO * (__expf(NORMC * dsh[nt][mt][r] - diag_s[nl] - kmax) + FEPS);
          hv[r] = (_Float16)val;
          lsum += val;
        }
        ks[mt] += lsum;
        *(h4*)&kpT[(mt * 16 + lm) * 136 + wave * 32 + nt * 16 + lg * 4] = hv;
      }
    __syncthreads();
#pragma unroll
    for (int k2 = 0; k2 < 4; ++k2) {
      h8 a2[2], b2[2];
#pragma unroll
      for (int mt2 = 0; mt2 < 2; ++mt2)
        a2[mt2] = *(const h8*)&kpT[(wave * 32 + mt2 * 16 + lm) * 136 + k2 * 32 + lg * 8];
#pragma unroll
      for (int dt = 0; dt < 2; ++dt)
        b2[dt] = *(const h8*)&vT_s[(dt * 16 + lm) * 136 + k2 * 32 + lg * 8];
#pragma unroll
      for (int mt2 = 0; mt2 < 2; ++mt2)
#pragma unroll
        for (int dt = 0; dt < 2; ++dt)
          cacc[mt2][dt] =
              __builtin_amdgcn_mfma_f32_16x16x32_f16(a2[mt2], b2[dt], cacc[mt2][dt], 0, 0, 0);
    }
    __syncthreads();
  }
  float* pp = part + (size_t)(blockIdx.y * 24 + blockIdx.x) * 4224;
#pragma unroll
  for (int mt2 = 0; mt2 < 2; ++mt2)
#pragma unroll
    for (int dt = 0; dt < 2; ++dt)
      *(f4*)(pp + (dt * 16 + lm) * 128 + wave * 32 + mt2 * 16 + lg * 4) = cacc[mt2][dt];
  float* redk = (float*)kpT;
#pragma unroll
  for (int mt = 0; mt < 8; ++mt) {
    float s = ks[mt];
    s += __shfl_xor(s, 16, 64);
    s += __shfl_xor(s, 32, 64);
    if (lg == 0) redk[wave * 128 + mt * 16 + lm] = s;
  }
  __syncthreads();
  if (t < 128)
    pp[32 * 128 + t] = redk[t] + redk[128 + t] + redk[256 + t] + redk[384 + t];
}

// ---------------------------------------------------------------- reduce partials
// -> ctxT_g fp16 [bh][d][m], ksum_g f32 [bh][m]
__global__ __launch_bounds__(256) void reduce_ctx(
    const float* __restrict__ part, _Float16* __restrict__ ctxT_g,
    float* __restrict__ ksum_g) {
  int bh = blockIdx.x >> 2, qtr = blockIdx.x & 3;
  int t = threadIdx.x;
  const float* pb = part + (size_t)bh * 24 * 4224;
  for (int it = 0; it < 5; ++it) {
    int lc = it * 256 + t;
    if (lc < 1056) {
      int cell = qtr * 1056 + lc;
      float s = 0.f;
      for (int p = 0; p < 24; ++p) s += pb[(size_t)p * 4224 + cell];
      int d = cell >> 7, m = cell & 127;
      if (d < 32) ctxT_g[(size_t)bh * 4096 + d * 128 + m] = (_Float16)s;
      else ksum_g[(size_t)bh * 128 + m] = s;
    }
  }
}

// ---------------------------------------------------------------- q side
__global__ __launch_bounds__(256) void attn_mfma(
    const _Float16* __restrict__ q, const _Float16* __restrict__ projh,
    const _Float16* __restrict__ ctxT_g, const float* __restrict__ ksum_g,
    _Float16* __restrict__ attn) {
  __shared__ __align__(16) _Float16 q_sh[128 * 32];
  __shared__ __align__(16) _Float16 qp_s[128 * 136];
  __shared__ float ksum_s[128];
  int n0 = blockIdx.x * 128;
  int bh = blockIdx.y, b = bh >> 3, h = bh & 7;
  int t = threadIdx.x, wave = t >> 6, lane = t & 63, lm = lane & 15, lg = lane >> 4;
  h8 pr[8];
#pragma unroll
  for (int mt = 0; mt < 8; ++mt) pr[mt] = *(const h8*)&projh[(mt * 16 + lm) * 32 + lg * 8];
  int scol = ((lane & 3) ^ ((lane >> 3) & 3)) * 8;
  const _Float16* gQ =
      q + ((size_t)(b * NTOT + n0 + wave * 32 + (lane >> 2))) * 256 + h * 32 + scol;
  gld16(gQ, q_sh + wave * 1024);
  gld16(gQ + 16 * 256, q_sh + wave * 1024 + 512);
  h8 ac[2][4];
#pragma unroll
  for (int dt = 0; dt < 2; ++dt)
#pragma unroll
    for (int k2 = 0; k2 < 4; ++k2)
      ac[dt][k2] = *(const h8*)&ctxT_g[(size_t)bh * 4096 + (dt * 16 + lm) * 128 + k2 * 32 + lg * 8];
  if (t < 128) ksum_s[t] = ksum_g[(size_t)bh * 128 + t];
  __syncthreads();
  int pg = (lg ^ ((lm >> 1) & 3)) * 8;
  float diag_r[2];
#pragma unroll
  for (int nt = 0; nt < 2; ++nt) {
    int n = wave * 32 + nt * 16 + lm;
    float s = 0.f;
#pragma unroll
    for (int c = 0; c < 4; ++c) {
      h8 qv = *(const h8*)&q_sh[n * 32 + c * 8];
#pragma unroll
      for (int j = 0; j < 8; ++j) s += (float)qv[j] * (float)qv[j];
    }
    diag_r[nt] = s * (0.5f * NORMC * NORMC);
  }
  f4 dsh[2][8];
#pragma unroll
  for (int nt = 0; nt < 2; ++nt) {
    h8 qf = *(const h8*)&q_sh[(wave * 32 + nt * 16 + lm) * 32 + pg];
#pragma unroll
    for (int mt = 0; mt < 8; ++mt) {
      f4 z = {0.f, 0.f, 0.f, 0.f};
      dsh[nt][mt] = __builtin_amdgcn_mfma_f32_16x16x32_f16(pr[mt], qf, z, 0, 0, 0);
    }
  }
  float den_r[2];
#pragma unroll
  for (int nt = 0; nt < 2; ++nt) {
    float mx = -1e30f;
#pragma unroll
    for (int mt = 0; mt < 8; ++mt)
#pragma unroll
      for (int r = 0; r < 4; ++r) mx = fmaxf(mx, dsh[nt][mt][r]);
    mx = fmaxf(mx, __shfl_xor(mx, 16, 64));
    mx = fmaxf(mx, __shfl_xor(mx, 32, 64));
    float den = 0.f;
#pragma unroll
    for (int mt = 0; mt < 8; ++mt) {
      h4 hv;
#pragma unroll
      for (int r = 0; r < 4; ++r) {
        float val = RATIO * (__expf(NORMC * (dsh[nt][mt][r] - mx) - diag_r[nt]) + FEPS);
        hv[r] = (_Float16)val;
        den += val * ksum_s[mt * 16 + lg * 4 + r];
      }
      *(h4*)&qp_s[(wave * 32 + nt * 16 + lm) * 136 + mt * 16 + lg * 4] = hv;
    }
    den += __shfl_xor(den, 16, 64);
    den += __shfl_xor(den, 32, 64);
    den_r[nt] = 1.f / den;
  }
  __syncthreads();
  f4 oacc[2][2] = {};
#pragma unroll
  for (int k2 = 0; k2 < 4; ++k2) {
    h8 bq[2];
#pragma unroll
    for (int nt = 0; nt < 2; ++nt)
      bq[nt] = *(const h8*)&qp_s[(wave * 32 + nt * 16 + lm) * 136 + k2 * 32 + lg * 8];
#pragma unroll
    for (int dt = 0; dt < 2; ++dt)
#pragma unroll
      for (int nt = 0; nt < 2; ++nt)
        oacc[dt][nt] = __builtin_amdgcn_mfma_f32_16x16x32_f16(ac[dt][k2], bq[nt], oacc[dt][nt], 0, 0, 0);
  }
#pragma unroll
  for (int dt = 0; dt < 2; ++dt)
#pragma unroll
    for (int nt = 0; nt < 2; ++nt) {
      int n = wave * 32 + nt * 16 + lm;
      h4 hv;
#pragma unroll
      for (int r = 0; r < 4; ++r) hv[r] = (_Float16)(oacc[dt][nt][r] * den_r[nt]);
      *(h4*)(attn + ((size_t)(b * NTOT + n0 + n)) * 256 + h * 32 + dt * 16 + lg * 4) = hv;
    }
}

// ---------------------------------------------------------------- output gemm
__global__ __launch_bounds__(256) void out_mfma(
    const _Float16* __restrict__ Wc, const _Float16* __restrict__ attn,
    const float* __restrict__ bc, float* __restrict__ out) {
  __shared__ __align__(16) _Float16 A_s[128 * 32];
  __shared__ __align__(16) _Float16 B_s[128 * 32];
  int bx = blockIdx.x;
  int o0 = blockIdx.y * 128;
  int b = bx / 72, nb0 = (bx % 72) * 128;
  int t = threadIdx.x, wave = t >> 6, lane = t & 63;
  int lm = lane & 15, lg = lane >> 4;
  int wm = (wave & 1) * 64, wn = (wave >> 1) * 64;
  int srow = wave * 32 + (lane >> 2);
  int scol = ((lane & 3) ^ ((lane >> 3) & 3)) * 8;
  const _Float16* gA = Wc + (size_t)(o0 + srow) * 256 + scol;
  const _Float16* gB = attn + (size_t)(b * NTOT + nb0 + srow) * 256 + scol;
  _Float16* lA = A_s + wave * 1024;
  _Float16* lB = B_s + wave * 1024;
  int pg = (lg ^ ((lm >> 1) & 3)) * 8;
  f4 acc[4][4] = {};
  for (int kt = 0; kt < 8; ++kt) {
    int c0 = kt * 32;
    __syncthreads();
    gld16(gA + c0, lA);
    gld16(gA + c0 + 16 * 256, lA + 512);
    gld16(gB + c0, lB);
    gld16(gB + c0 + 16 * 256, lB + 512);
    __syncthreads();
    h8 a[4], bf[4];
#pragma unroll
    for (int mi = 0; mi < 4; ++mi) a[mi] = *(const h8*)&A_s[(wm + mi * 16 + lm) * 32 + pg];
#pragma unroll
    for (int ni = 0; ni < 4; ++ni) bf[ni] = *(const h8*)&B_s[(wn + ni * 16 + lm) * 32 + pg];
#pragma unroll
    for (int mi = 0; mi < 4; ++mi)
#pragma unroll
      for (int ni = 0; ni < 4; ++ni)
        acc[mi][ni] = __builtin_amdgcn_mfma_f32_16x16x32_f16(bf[ni], a[mi], acc[mi][ni], 0, 0, 0);
  }
#pragma unroll
  for (int mi = 0; mi < 4; ++mi) {
    int o = o0 + wm + mi * 16 + lm;
    float bias = bc[o];
#pragma unroll
    for (int ni = 0; ni < 4; ++ni) {
      f4 ov = acc[mi][ni];
      float4 st = make_float4(ov[0] + bias, ov[1] + bias, ov[2] + bias, ov[3] + bias);
      *(float4*)(out + ((size_t)(b * 256 + o)) * NTOT + nb0 + wn + ni * 16 + lg * 4) = st;
    }
  }
}

// ---------------------------------------------------------------- launch
extern "C" void kernel_launch(void* const* d_in, const int* in_sizes, int n_in,
                              void* d_out, int out_size, void* d_ws, size_t ws_size,
                              hipStream_t stream) {
  const float* x = (const float*)d_in[0];
  const float* wq = (const float*)d_in[1];
  const float* wk = (const float*)d_in[2];
  const float* wv = (const float*)d_in[3];
  const float* wo = (const float*)d_in[4];
  const float* bo = (const float*)d_in[5];
  const float* proj = (const float*)d_in[6];
  const float* wp = (const float*)d_in[7];
  const float* bp = (const float*)d_in[8];
  float* out = (float*)d_out;
  float* ws = (float*)d_ws;

  float* part = ws;                        // 768*4224 = 3,244,032
  float* kmaxp = part + 3244032;           // 32*72 = 2304
  float* ksum_g = kmaxp + 2304;            // 32*128 = 4096
  float* bc = ksum_g + 4096;               // 256
  _Float16* hb = (_Float16*)(bc + 256);
  const size_t THALF = (size_t)4 * NTOT * 256;  // 9,437,184
  _Float16* q_h = hb;
  _Float16* k_h = q_h + THALF;
  _Float16* xT = k_h + THALF;          // reused as attn fp16 output
  _Float16* vTg = xT + THALF;          // v transposed [b*256+c][n]
  _Float16* Wall = vTg + THALF;        // 768*256
  _Float16* Wc = Wall + 768 * 256;     // 256*256
  _Float16* projh = Wc + 65536;        // 128*32
  _Float16* ctxT_g = projh + 4096;     // 32*4096

  prep<<<3344, 256, 0, stream>>>(x, wq, wk, wv, proj, wo, bo, wp, bp,
                                 xT, Wall, projh, Wc, bc);
  qkv_mfma<<<dim3(288, 2, 3), 256, 0, stream>>>(xT, Wall, projh, q_h, k_h, vTg, kmaxp);
  ctx_mfma<<<dim3(24, 32), 256, 0, stream>>>(k_h, vTg, projh, kmaxp, part);
  reduce_ctx<<<128, 256, 0, stream>>>(part, ctxT_g, ksum_g);
  attn_mfma<<<dim3(72, 32), 256, 0, stream>>>(q_h, projh, ctxT_g, ksum_g, xT);
  out_mfma<<<dim3(288, 2), 256, 0, stream>>>(Wc, xT, bc, out);
}